// Round 3
// baseline (369.768 us; speedup 1.0000x reference)
//
#include <hip/hip_runtime.h>

// BatchNorm2d training-mode forward, fp32, NCHW.
// B=64, C=256, H=56, W=56. Layout: idx = ((b*C + c)*H + h)*W + w.
// Plane (b,c) is contiguous HW=3136 floats => 784 float4.
// C=256 is a power of two: plane = b*C + c  =>  c = plane & 255, b = plane >> 8.

#define EPS 1e-5f
constexpr int B_ = 64;
constexpr int C_ = 256;
constexpr int HW_ = 56 * 56;            // 3136
constexpr int HW4_ = HW_ / 4;           // 784 = 3*256 + 16
constexpr int NPC_ = B_ * HW_;          // 200704 elements per channel
constexpr int NPLANES_ = B_ * C_;       // 16384

// native clang vector type — __builtin_nontemporal_store rejects HIP_vector_type
typedef float vf4 __attribute__((ext_vector_type(4)));

// ---------------- Kernel 1: per-plane partial sum / sumsq ----------------
// One block per (b,c) plane; planes are contiguous in memory.
// 784 float4 / 256 threads: 3 full rounds + 16-thread tail, loads issued up front.
__global__ void __launch_bounds__(256) bn_partial(const float* __restrict__ x,
                                                  float* __restrict__ psum,
                                                  float* __restrict__ psumsq) {
    const int plane = blockIdx.x;                       // 0 .. B*C-1
    const int t = threadIdx.x;
    const float4* xp = (const float4*)(x + (size_t)plane * HW_);

    // always-valid loads (t+512 <= 767 < 784)
    float4 v0 = xp[t];
    float4 v1 = xp[t + 256];
    float4 v2 = xp[t + 512];

    float s, ss;
    s  = v0.x + v0.y + v0.z + v0.w;
    ss = v0.x * v0.x + v0.y * v0.y + v0.z * v0.z + v0.w * v0.w;
    s  += v1.x + v1.y + v1.z + v1.w;
    ss += v1.x * v1.x + v1.y * v1.y + v1.z * v1.z + v1.w * v1.w;
    s  += v2.x + v2.y + v2.z + v2.w;
    ss += v2.x * v2.x + v2.y * v2.y + v2.z * v2.z + v2.w * v2.w;

    if (t < HW4_ - 768) {                               // 16-thread tail
        float4 v3 = xp[t + 768];
        s  += v3.x + v3.y + v3.z + v3.w;
        ss += v3.x * v3.x + v3.y * v3.y + v3.z * v3.z + v3.w * v3.w;
    }

    // wave-64 reduce
    for (int off = 32; off > 0; off >>= 1) {
        s  += __shfl_down(s, off);
        ss += __shfl_down(ss, off);
    }
    __shared__ float ls[8];
    const int wave = t >> 6;
    const int lane = t & 63;
    if (lane == 0) { ls[wave] = s; ls[4 + wave] = ss; }
    __syncthreads();
    if (t == 0) {
        float S  = ls[0] + ls[1] + ls[2] + ls[3];
        float SS = ls[4] + ls[5] + ls[6] + ls[7];
        const int c = plane & (C_ - 1);
        const int b = plane >> 8;
        // transpose so a channel's 64 partials are contiguous for kernel 2
        psum[c * B_ + b]   = S;
        psumsq[c * B_ + b] = SS;
    }
}

// ---------------- Kernel 2: per-channel finalize -> scale/shift ----------------
// grid = C blocks, 64 threads (one wave) each.
__global__ void __launch_bounds__(64) bn_finalize(const float* __restrict__ psum,
                                                  const float* __restrict__ psumsq,
                                                  const float* __restrict__ gamma,
                                                  const float* __restrict__ beta,
                                                  float* __restrict__ scale,
                                                  float* __restrict__ shift) {
    const int c = blockIdx.x;
    const int t = threadIdx.x;   // 0..63
    float s  = psum[c * B_ + t];
    float ss = psumsq[c * B_ + t];
    for (int off = 32; off > 0; off >>= 1) {
        s  += __shfl_down(s, off);
        ss += __shfl_down(ss, off);
    }
    if (t == 0) {
        const float invN = 1.0f / (float)NPC_;
        float mean = s * invN;
        float var  = ss * invN - mean * mean;
        float sc   = gamma[c] * rsqrtf(var + EPS);
        scale[c] = sc;
        shift[c] = beta[c] - mean * sc;
    }
}

// ---------------- Kernel 3: elementwise apply, per-plane blocks ----------------
// One block per plane: c is block-uniform => scalar loads of scale/shift.
// x reads should hit L3 (warmed by kernel 1); out stores are non-temporal so the
// 196 MiB of write traffic does NOT evict the x tail from Infinity Cache.
__global__ void __launch_bounds__(256) bn_apply(const float* __restrict__ x,
                                                const float* __restrict__ scale,
                                                const float* __restrict__ shift,
                                                float* __restrict__ out) {
    const int plane = blockIdx.x;
    const int t = threadIdx.x;
    const int c = plane & (C_ - 1);
    const float sc = scale[c];
    const float sh = shift[c];

    const float4* xp = (const float4*)(x + (size_t)plane * HW_);
    float* op = out + (size_t)plane * HW_;

    float4 v0 = xp[t];
    float4 v1 = xp[t + 256];
    float4 v2 = xp[t + 512];

    vf4 o0, o1, o2;
    o0.x = fmaf(v0.x, sc, sh); o0.y = fmaf(v0.y, sc, sh);
    o0.z = fmaf(v0.z, sc, sh); o0.w = fmaf(v0.w, sc, sh);
    o1.x = fmaf(v1.x, sc, sh); o1.y = fmaf(v1.y, sc, sh);
    o1.z = fmaf(v1.z, sc, sh); o1.w = fmaf(v1.w, sc, sh);
    o2.x = fmaf(v2.x, sc, sh); o2.y = fmaf(v2.y, sc, sh);
    o2.z = fmaf(v2.z, sc, sh); o2.w = fmaf(v2.w, sc, sh);

    __builtin_nontemporal_store(o0, (vf4*)op + t);
    __builtin_nontemporal_store(o1, (vf4*)op + t + 256);
    __builtin_nontemporal_store(o2, (vf4*)op + t + 512);

    if (t < HW4_ - 768) {
        float4 v3 = xp[t + 768];
        vf4 o3;
        o3.x = fmaf(v3.x, sc, sh); o3.y = fmaf(v3.y, sc, sh);
        o3.z = fmaf(v3.z, sc, sh); o3.w = fmaf(v3.w, sc, sh);
        __builtin_nontemporal_store(o3, (vf4*)op + t + 768);
    }
}

extern "C" void kernel_launch(void* const* d_in, const int* in_sizes, int n_in,
                              void* d_out, int out_size, void* d_ws, size_t ws_size,
                              hipStream_t stream) {
    const float* x     = (const float*)d_in[0];
    const float* gamma = (const float*)d_in[1];
    const float* beta  = (const float*)d_in[2];
    float* out = (float*)d_out;

    // workspace layout (floats): psum[B*C] | psumsq[B*C] | scale[C] | shift[C]
    float* psum   = (float*)d_ws;
    float* psumsq = psum + B_ * C_;
    float* scale  = psumsq + B_ * C_;
    float* shift  = scale + C_;

    bn_partial<<<NPLANES_, 256, 0, stream>>>(x, psum, psumsq);
    bn_finalize<<<C_, 64, 0, stream>>>(psum, psumsq, gamma, beta, scale, shift);
    bn_apply<<<NPLANES_, 256, 0, stream>>>(x, scale, shift, out);
}